// Round 1
// baseline (4443.684 us; speedup 1.0000x reference)
//
#include <hip/hip_runtime.h>
#include <math.h>

#define B_    32
#define T_    512
#define WDIM_ 300
#define H_    256
#define G4_   1024            // 4*H
#define M_    (B_ * T_)       // 16384

// ---------------------------------------------------------------------------
// Kernel 1: z = relu(emb[x] @ W_in + b_in)   [16384,300]@[300,256]
// 128x128 tiles, KC=16 (K padded 300->304 with guards), 256 thr, 8x8/thread
// ---------------------------------------------------------------------------
__global__ __launch_bounds__(256)
void k_embed_proj(const float* __restrict__ emb, const float* __restrict__ Win,
                  const float* __restrict__ bin, const int* __restrict__ x,
                  float* __restrict__ z)
{
    __shared__ float Ash[16][132];
    __shared__ float Bsh[16][132];
    __shared__ int   rows[128];

    const int tid = threadIdx.x;
    const int tx = tid & 15, ty = tid >> 4;
    const int rm = blockIdx.y * 128;
    const int cn = blockIdx.x * 128;

    if (tid < 128) rows[tid] = x[rm + tid];
    __syncthreads();

    float acc[8][8];
#pragma unroll
    for (int i = 0; i < 8; ++i)
#pragma unroll
        for (int j = 0; j < 8; ++j) acc[i][j] = 0.f;

    for (int kc = 0; kc < 19; ++kc) {
        const int k0 = kc * 16;
        // A tile (gathered embedding rows), stored transposed: Ash[kk][r]
#pragma unroll
        for (int e = 0; e < 8; ++e) {
            const int idx = e * 256 + tid;
            const int r = idx >> 4, kk = idx & 15;
            const int k = k0 + kk;
            const int v = rows[r];
            Ash[kk][r] = (k < WDIM_) ? emb[(size_t)v * WDIM_ + k] : 0.f;
        }
        // B tile: Bsh[kk][n]
#pragma unroll
        for (int e = 0; e < 8; ++e) {
            const int idx = e * 256 + tid;
            const int kk = idx >> 7, n = idx & 127;
            const int k = k0 + kk;
            Bsh[kk][n] = (k < WDIM_) ? Win[(size_t)k * H_ + cn + n] : 0.f;
        }
        __syncthreads();
#pragma unroll
        for (int kk = 0; kk < 16; ++kk) {
            float a[8], bb[8];
#pragma unroll
            for (int i = 0; i < 8; ++i) a[i] = Ash[kk][ty * 8 + i];
#pragma unroll
            for (int j = 0; j < 8; ++j) bb[j] = Bsh[kk][tx * 8 + j];
#pragma unroll
            for (int i = 0; i < 8; ++i)
#pragma unroll
                for (int j = 0; j < 8; ++j) acc[i][j] += a[i] * bb[j];
        }
        __syncthreads();
    }

#pragma unroll
    for (int i = 0; i < 8; ++i) {
        const int row = rm + ty * 8 + i;
#pragma unroll
        for (int j = 0; j < 8; ++j) {
            const int col = cn + tx * 8 + j;
            z[(size_t)row * H_ + col] = fmaxf(acc[i][j] + bin[col], 0.f);
        }
    }
}

// ---------------------------------------------------------------------------
// Kernel 2: P_d = z @ Wih_d + bl_d  (both directions via blockIdx.z)
// [16384,256]@[256,1024], 128x128 tiles, KC=16, 256 thr, 8x8/thread
// ---------------------------------------------------------------------------
__global__ __launch_bounds__(256)
void k_in_proj(const float* __restrict__ z,
               const float* __restrict__ Wf, const float* __restrict__ blf,
               const float* __restrict__ Wb, const float* __restrict__ blb,
               float* __restrict__ Pf, float* __restrict__ Pb)
{
    const float* W  = blockIdx.z ? Wb  : Wf;
    const float* bl = blockIdx.z ? blb : blf;
    float*       P  = blockIdx.z ? Pb  : Pf;

    __shared__ float Ash[16][132];
    __shared__ float Bsh[16][132];

    const int tid = threadIdx.x;
    const int tx = tid & 15, ty = tid >> 4;
    const int rm = blockIdx.y * 128;
    const int cn = blockIdx.x * 128;

    float acc[8][8];
#pragma unroll
    for (int i = 0; i < 8; ++i)
#pragma unroll
        for (int j = 0; j < 8; ++j) acc[i][j] = 0.f;

    for (int kc = 0; kc < 16; ++kc) {
        const int k0 = kc * 16;
#pragma unroll
        for (int e = 0; e < 8; ++e) {
            const int idx = e * 256 + tid;
            const int r = idx >> 4, kk = idx & 15;
            Ash[kk][r] = z[(size_t)(rm + r) * H_ + k0 + kk];
        }
#pragma unroll
        for (int e = 0; e < 8; ++e) {
            const int idx = e * 256 + tid;
            const int kk = idx >> 7, n = idx & 127;
            Bsh[kk][n] = W[(size_t)(k0 + kk) * G4_ + cn + n];
        }
        __syncthreads();
#pragma unroll
        for (int kk = 0; kk < 16; ++kk) {
            float a[8], bb[8];
#pragma unroll
            for (int i = 0; i < 8; ++i) a[i] = Ash[kk][ty * 8 + i];
#pragma unroll
            for (int j = 0; j < 8; ++j) bb[j] = Bsh[kk][tx * 8 + j];
#pragma unroll
            for (int i = 0; i < 8; ++i)
#pragma unroll
                for (int j = 0; j < 8; ++j) acc[i][j] += a[i] * bb[j];
        }
        __syncthreads();
    }

#pragma unroll
    for (int i = 0; i < 8; ++i) {
        const int row = rm + ty * 8 + i;
#pragma unroll
        for (int j = 0; j < 8; ++j) {
            const int col = cn + tx * 8 + j;
            P[(size_t)row * G4_ + col] = acc[i][j] + bl[col];
        }
    }
}

// ---------------------------------------------------------------------------
// Kernel 3: masked bidirectional LSTM recurrence + masked-sum pooling.
// One WG per (dir, batch-row): 64 WGs x 1024 threads, no cross-WG sync.
// Thread (q = tid>>8, j = tid&255): k-range [64q, 64q+64), columns [4j,4j+4).
// Partial gate sums reduced via LDS; first 256 threads do the cell update.
// Mask is a contiguous prefix (t < len), so we iterate only valid steps.
// ---------------------------------------------------------------------------
__global__ __launch_bounds__(1024)
void k_lstm(const float* __restrict__ Pf, const float* __restrict__ Pb,
            const float* __restrict__ Whf, const float* __restrict__ Whb,
            const int* __restrict__ lengths, float* __restrict__ pool)
{
    __shared__ float h_sh[256];
    __shared__ float c_sh[256];
    __shared__ float zp[4][1024];

    const int tid = threadIdx.x;
    const int wg  = blockIdx.x;      // 0..63
    const int dir = wg & 1;
    const int b   = wg >> 1;

    const float* P   = dir ? Pb  : Pf;
    const float* Whh = dir ? Whb : Whf;
    const int    len = lengths[b];

    const int q  = tid >> 8;         // 0..3  k-quarter
    const int j4 = (tid & 255) << 2; // column group base
    const float* Wq = Whh + (size_t)(q * 64) * G4_ + j4;
    const float* hq = h_sh + q * 64;

    if (tid < 256) { h_sh[tid] = 0.f; c_sh[tid] = 0.f; }
    float pa = 0.f;
    __syncthreads();

    for (int s = 0; s < len; ++s) {
        const int t = dir ? (len - 1 - s) : s;
        const size_t prow = (size_t)(b * T_ + t) * G4_;

        // input-projection row (bias already folded in) — first 256 threads
        float pv0 = 0.f, pv1 = 0.f, pv2 = 0.f, pv3 = 0.f;
        if (tid < 256) {
            const float* pr = P + prow + tid;
            pv0 = pr[0]; pv1 = pr[256]; pv2 = pr[512]; pv3 = pr[768];
        }

        if (s > 0) {
            float a0 = 0.f, a1 = 0.f, a2 = 0.f, a3 = 0.f;
#pragma unroll 8
            for (int k = 0; k < 64; ++k) {
                const float  hv = hq[k];
                const float4 w  = *(const float4*)(Wq + (size_t)k * G4_);
                a0 += hv * w.x; a1 += hv * w.y; a2 += hv * w.z; a3 += hv * w.w;
            }
            float4 zr; zr.x = a0; zr.y = a1; zr.z = a2; zr.w = a3;
            *(float4*)&zp[q][j4] = zr;
        }
        __syncthreads();

        if (tid < 256) {
            const int d = tid;
            float zi = pv0, zf = pv1, zg = pv2, zo = pv3;
            if (s > 0) {
                zi += zp[0][d]       + zp[1][d]       + zp[2][d]       + zp[3][d];
                zf += zp[0][256 + d] + zp[1][256 + d] + zp[2][256 + d] + zp[3][256 + d];
                zg += zp[0][512 + d] + zp[1][512 + d] + zp[2][512 + d] + zp[3][512 + d];
                zo += zp[0][768 + d] + zp[1][768 + d] + zp[2][768 + d] + zp[3][768 + d];
            }
            const float ig = 1.f / (1.f + expf(-zi));
            const float fg = 1.f / (1.f + expf(-zf));
            const float gg = tanhf(zg);
            const float og = 1.f / (1.f + expf(-zo));
            const float cn = fg * c_sh[d] + ig * gg;
            const float hn = og * tanhf(cn);
            c_sh[d] = cn;
            h_sh[d] = hn;
            pa += hn;
        }
        __syncthreads();
    }

    if (tid < 256)
        pool[b * 512 + dir * 256 + tid] = pa / (float)len;
}

// ---------------------------------------------------------------------------
// Kernel 4: fc_hidden = relu(pool @ Wfc + bfc); out = fc_hidden @ Wout + bout
// One WG per batch row, 256 threads.
// ---------------------------------------------------------------------------
__global__ __launch_bounds__(256)
void k_fc(const float* __restrict__ pool, const float* __restrict__ Wfc,
          const float* __restrict__ bfc, const float* __restrict__ Wout,
          const float* __restrict__ bout, float* __restrict__ out)
{
    __shared__ float p_sh[512];
    __shared__ float red[8];

    const int tid = threadIdx.x;
    const int b   = blockIdx.x;

    p_sh[tid]       = pool[b * 512 + tid];
    p_sh[256 + tid] = pool[b * 512 + 256 + tid];
    __syncthreads();

    float acc = bfc[tid];
#pragma unroll 8
    for (int k = 0; k < 512; ++k)
        acc += p_sh[k] * Wfc[(size_t)k * H_ + tid];
    const float fh = fmaxf(acc, 0.f);

    float p0 = fh * Wout[tid * 2 + 0];
    float p1 = fh * Wout[tid * 2 + 1];
#pragma unroll
    for (int off = 32; off > 0; off >>= 1) {
        p0 += __shfl_down(p0, off);
        p1 += __shfl_down(p1, off);
    }
    const int wave = tid >> 6;
    if ((tid & 63) == 0) { red[wave * 2] = p0; red[wave * 2 + 1] = p1; }
    __syncthreads();
    if (tid == 0) {
        out[b * 2 + 0] = red[0] + red[2] + red[4] + red[6] + bout[0];
        out[b * 2 + 1] = red[1] + red[3] + red[5] + red[7] + bout[1];
    }
}

// Sentinel if workspace is too small (diagnosable absmax ~1e9)
__global__ void k_sentinel(float* out, int n)
{
    const int i = blockIdx.x * blockDim.x + threadIdx.x;
    if (i < n) out[i] = 1.0e9f;
}

extern "C" void kernel_launch(void* const* d_in, const int* in_sizes, int n_in,
                              void* d_out, int out_size, void* d_ws, size_t ws_size,
                              hipStream_t stream)
{
    const float* emb  = (const float*)d_in[0];
    const float* Win  = (const float*)d_in[1];
    const float* bin  = (const float*)d_in[2];
    const float* Wihf = (const float*)d_in[3];
    const float* Whhf = (const float*)d_in[4];
    const float* blf  = (const float*)d_in[5];
    const float* Wihb = (const float*)d_in[6];
    const float* Whhb = (const float*)d_in[7];
    const float* blb  = (const float*)d_in[8];
    const float* Wfc  = (const float*)d_in[9];
    const float* bfc  = (const float*)d_in[10];
    const float* Wout = (const float*)d_in[11];
    const float* bout = (const float*)d_in[12];
    const int*   x    = (const int*)d_in[13];
    // d_in[14] = mask: unused (mask[b,t] == (t < lengths[b]) by construction)
    const int*   lens = (const int*)d_in[15];
    float*       out  = (float*)d_out;

    const size_t need = ((size_t)M_ * H_ + 2 * (size_t)M_ * G4_ + 32 * 512) * sizeof(float);
    if (ws_size < need) {
        hipLaunchKernelGGL(k_sentinel, dim3(1), dim3(64), 0, stream, out, out_size);
        return;
    }

    float* z    = (float*)d_ws;                  // [16384,256]
    float* Pf   = z  + (size_t)M_ * H_;          // [16384,1024]
    float* Pb   = Pf + (size_t)M_ * G4_;         // [16384,1024]
    float* pool = Pb + (size_t)M_ * G4_;         // [32,512]

    hipLaunchKernelGGL(k_embed_proj, dim3(2, 128), dim3(256), 0, stream,
                       emb, Win, bin, x, z);
    hipLaunchKernelGGL(k_in_proj, dim3(8, 128, 2), dim3(256), 0, stream,
                       z, Wihf, blf, Wihb, blb, Pf, Pb);
    hipLaunchKernelGGL(k_lstm, dim3(64), dim3(1024), 0, stream,
                       Pf, Pb, Whhf, Whhb, lens, pool);
    hipLaunchKernelGGL(k_fc, dim3(32), dim3(256), 0, stream,
                       pool, Wfc, bfc, Wout, bout, out);
}

// Round 2
// 2704.731 us; speedup vs baseline: 1.6429x; 1.6429x over previous
//
#include <hip/hip_runtime.h>
#include <math.h>

#define B_    32
#define T_    512
#define WDIM_ 300
#define H_    256
#define G4_   1024            // 4*H
#define M_    (B_ * T_)       // 16384

// persistent-LSTM geometry
#define NBG   16              // batch groups (2 rows each)
#define NCG   4               // col groups per team (64 d's each)
#define NTEAM 32              // 2 dirs * NBG
#define NWG   128             // NTEAM * NCG
#define THR   512

// ---------------------------------------------------------------------------
// Kernel 1: z = relu(emb[x] @ W_in + b_in)   [16384,300]@[300,256]
// ---------------------------------------------------------------------------
__global__ __launch_bounds__(256)
void k_embed_proj(const float* __restrict__ emb, const float* __restrict__ Win,
                  const float* __restrict__ bin, const int* __restrict__ x,
                  float* __restrict__ z)
{
    __shared__ float Ash[16][132];
    __shared__ float Bsh[16][132];
    __shared__ int   rows[128];

    const int tid = threadIdx.x;
    const int tx = tid & 15, ty = tid >> 4;
    const int rm = blockIdx.y * 128;
    const int cn = blockIdx.x * 128;

    if (tid < 128) rows[tid] = x[rm + tid];
    __syncthreads();

    float acc[8][8];
#pragma unroll
    for (int i = 0; i < 8; ++i)
#pragma unroll
        for (int j = 0; j < 8; ++j) acc[i][j] = 0.f;

    for (int kc = 0; kc < 19; ++kc) {
        const int k0 = kc * 16;
#pragma unroll
        for (int e = 0; e < 8; ++e) {
            const int idx = e * 256 + tid;
            const int r = idx >> 4, kk = idx & 15;
            const int k = k0 + kk;
            const int v = rows[r];
            Ash[kk][r] = (k < WDIM_) ? emb[(size_t)v * WDIM_ + k] : 0.f;
        }
#pragma unroll
        for (int e = 0; e < 8; ++e) {
            const int idx = e * 256 + tid;
            const int kk = idx >> 7, n = idx & 127;
            const int k = k0 + kk;
            Bsh[kk][n] = (k < WDIM_) ? Win[(size_t)k * H_ + cn + n] : 0.f;
        }
        __syncthreads();
#pragma unroll
        for (int kk = 0; kk < 16; ++kk) {
            float a[8], bb[8];
#pragma unroll
            for (int i = 0; i < 8; ++i) a[i] = Ash[kk][ty * 8 + i];
#pragma unroll
            for (int j = 0; j < 8; ++j) bb[j] = Bsh[kk][tx * 8 + j];
#pragma unroll
            for (int i = 0; i < 8; ++i)
#pragma unroll
                for (int j = 0; j < 8; ++j) acc[i][j] += a[i] * bb[j];
        }
        __syncthreads();
    }

#pragma unroll
    for (int i = 0; i < 8; ++i) {
        const int row = rm + ty * 8 + i;
#pragma unroll
        for (int j = 0; j < 8; ++j) {
            const int col = cn + tx * 8 + j;
            z[(size_t)row * H_ + col] = fmaxf(acc[i][j] + bin[col], 0.f);
        }
    }
}

// ---------------------------------------------------------------------------
// Kernel 2: P_d = z @ Wih_d + bl_d  (both directions via blockIdx.z)
// ---------------------------------------------------------------------------
__global__ __launch_bounds__(256)
void k_in_proj(const float* __restrict__ z,
               const float* __restrict__ Wf, const float* __restrict__ blf,
               const float* __restrict__ Wb, const float* __restrict__ blb,
               float* __restrict__ Pf, float* __restrict__ Pb)
{
    const float* W  = blockIdx.z ? Wb  : Wf;
    const float* bl = blockIdx.z ? blb : blf;
    float*       P  = blockIdx.z ? Pb  : Pf;

    __shared__ float Ash[16][132];
    __shared__ float Bsh[16][132];

    const int tid = threadIdx.x;
    const int tx = tid & 15, ty = tid >> 4;
    const int rm = blockIdx.y * 128;
    const int cn = blockIdx.x * 128;

    float acc[8][8];
#pragma unroll
    for (int i = 0; i < 8; ++i)
#pragma unroll
        for (int j = 0; j < 8; ++j) acc[i][j] = 0.f;

    for (int kc = 0; kc < 16; ++kc) {
        const int k0 = kc * 16;
#pragma unroll
        for (int e = 0; e < 8; ++e) {
            const int idx = e * 256 + tid;
            const int r = idx >> 4, kk = idx & 15;
            Ash[kk][r] = z[(size_t)(rm + r) * H_ + k0 + kk];
        }
#pragma unroll
        for (int e = 0; e < 8; ++e) {
            const int idx = e * 256 + tid;
            const int kk = idx >> 7, n = idx & 127;
            Bsh[kk][n] = W[(size_t)(k0 + kk) * G4_ + cn + n];
        }
        __syncthreads();
#pragma unroll
        for (int kk = 0; kk < 16; ++kk) {
            float a[8], bb[8];
#pragma unroll
            for (int i = 0; i < 8; ++i) a[i] = Ash[kk][ty * 8 + i];
#pragma unroll
            for (int j = 0; j < 8; ++j) bb[j] = Bsh[kk][tx * 8 + j];
#pragma unroll
            for (int i = 0; i < 8; ++i)
#pragma unroll
                for (int j = 0; j < 8; ++j) acc[i][j] += a[i] * bb[j];
        }
        __syncthreads();
    }

#pragma unroll
    for (int i = 0; i < 8; ++i) {
        const int row = rm + ty * 8 + i;
#pragma unroll
        for (int j = 0; j < 8; ++j) {
            const int col = cn + tx * 8 + j;
            P[(size_t)row * G4_ + col] = acc[i][j] + bl[col];
        }
    }
}

// ---------------------------------------------------------------------------
// Init: zero h double-buffers and team barrier counters (ws is 0xAA-poisoned)
// ---------------------------------------------------------------------------
__global__ void k_init(float* __restrict__ hb, unsigned int* __restrict__ ctr)
{
    const int i = blockIdx.x * blockDim.x + threadIdx.x;
    if (i < 2 * 2 * B_ * H_) hb[i] = 0.f;          // [dir][buf][32][256]
    if (i < NTEAM * 512)     ctr[i] = 0u;
}

// ---------------------------------------------------------------------------
// Kernel 3: persistent bidirectional LSTM recurrence.
// WG = (dir, batch-pair bg, colgroup cg of 64 d's). Team = 4 colgroups.
// Whh slice register-resident (2 cols x 64 k per thread, loaded once).
// Per step: h via broadcast float4 global loads, 4-way k-split reduced in LDS,
// gates on first 128 threads, h double-buffered in global, one team barrier
// per step (atomic counter + agent release/acquire fences).
// ---------------------------------------------------------------------------
__global__ __launch_bounds__(THR, 2)
void k_lstm_persist(const float* __restrict__ Pf, const float* __restrict__ Pb,
                    const float* __restrict__ Whf, const float* __restrict__ Whb,
                    const int* __restrict__ lengths,
                    float* __restrict__ hb, unsigned int* __restrict__ ctr,
                    float* __restrict__ pool)
{
    __shared__ float zp[4][2][256];   // [ksplit][row][local gate-col]

    const int tid  = threadIdx.x;
    const int wg   = blockIdx.x;
    const int bg   = wg & 15;
    const int dir  = (wg >> 4) & 1;
    const int cg   = wg >> 5;         // teammates differ only in cg (stride 32)
    const int team = wg & 31;

    const float* P   = dir ? Pb  : Pf;
    const float* Whh = dir ? Whb : Whf;

    const int brow0 = bg * 2, brow1 = bg * 2 + 1;
    const int len0 = lengths[brow0], len1 = lengths[brow1];
    const int tmax = max(len0, len1);

    // GEMM mapping: q = k-quarter, c2 -> local cols (2*c2, 2*c2+1) in [0,256)
    const int q   = tid >> 7;
    const int c2  = tid & 127;
    const int c0  = c2 * 2;
    const int g0  = c0 >> 6;
    const int dd0 = c0 & 63;
    const int gcol0 = g0 * 256 + cg * 64 + dd0;   // global col; +1 never crosses gate

    // persistent W slice: 128 VGPRs
    float w0[64], w1[64];
    {
        const float* wp = Whh + (size_t)(q * 64) * G4_ + gcol0;
#pragma unroll
        for (int k = 0; k < 64; ++k) {
            w0[k] = wp[(size_t)k * G4_];
            w1[k] = wp[(size_t)k * G4_ + 1];
        }
    }

    // gate mapping (tid < 128): row gr, hidden index gdd
    const int gr    = tid >> 6;
    const int gdd   = tid & 63;
    const int gbrow = bg * 2 + gr;
    const int glen  = gr ? len1 : len0;
    float cst = 0.f, hreg = 0.f, pacc = 0.f;

    unsigned int* tc  = ctr + team * 512;
    float*        hbD = hb + (size_t)dir * 2 * B_ * H_;   // [buf][32][256]

    for (int s = 0; s < tmax; ++s) {
        const int tt = dir ? (tmax - 1 - s) : s;

        // prefetch input projection for this step (independent of barrier)
        float pv0 = 0.f, pv1 = 0.f, pv2 = 0.f, pv3 = 0.f;
        if (tid < 128) {
            const float* pr = P + (size_t)(gbrow * T_ + tt) * G4_ + cg * 64 + gdd;
            pv0 = pr[0]; pv1 = pr[256]; pv2 = pr[512]; pv3 = pr[768];
        }

        // wait for teammates' h of previous step
        if (s > 0) {
            if (tid == 0) {
                while (__hip_atomic_load(&tc[s - 1], __ATOMIC_RELAXED,
                                         __HIP_MEMORY_SCOPE_AGENT) < NCG) {
                    __builtin_amdgcn_s_sleep(1);
                }
                __builtin_amdgcn_fence(__ATOMIC_ACQUIRE, "agent");
            }
            __syncthreads();
        }

        // GEMM: 2 rows x 2 cols over k in [64q, 64q+64)
        const float* h0p = hbD + (size_t)(s & 1) * B_ * H_ + brow0 * H_ + q * 64;
        const float* h1p = h0p + H_;
        float a00 = 0.f, a01 = 0.f, a10 = 0.f, a11 = 0.f;
#pragma unroll
        for (int k4 = 0; k4 < 16; ++k4) {
            const float4 hv0 = *(const float4*)(h0p + k4 * 4);
            const float4 hv1 = *(const float4*)(h1p + k4 * 4);
            a00 += hv0.x * w0[k4*4+0]; a01 += hv0.x * w1[k4*4+0];
            a10 += hv1.x * w0[k4*4+0]; a11 += hv1.x * w1[k4*4+0];
            a00 += hv0.y * w0[k4*4+1]; a01 += hv0.y * w1[k4*4+1];
            a10 += hv1.y * w0[k4*4+1]; a11 += hv1.y * w1[k4*4+1];
            a00 += hv0.z * w0[k4*4+2]; a01 += hv0.z * w1[k4*4+2];
            a10 += hv1.z * w0[k4*4+2]; a11 += hv1.z * w1[k4*4+2];
            a00 += hv0.w * w0[k4*4+3]; a01 += hv0.w * w1[k4*4+3];
            a10 += hv1.w * w0[k4*4+3]; a11 += hv1.w * w1[k4*4+3];
        }
        *(float2*)&zp[q][0][c0] = make_float2(a00, a01);
        *(float2*)&zp[q][1][c0] = make_float2(a10, a11);
        __syncthreads();

        // gates + state update + h publish
        if (tid < 128) {
            const int ci = gdd;
            float zi = pv0 + zp[0][gr][ci]       + zp[1][gr][ci]       + zp[2][gr][ci]       + zp[3][gr][ci];
            float zf = pv1 + zp[0][gr][64 + ci]  + zp[1][gr][64 + ci]  + zp[2][gr][64 + ci]  + zp[3][gr][64 + ci];
            float zg = pv2 + zp[0][gr][128 + ci] + zp[1][gr][128 + ci] + zp[2][gr][128 + ci] + zp[3][gr][128 + ci];
            float zo = pv3 + zp[0][gr][192 + ci] + zp[1][gr][192 + ci] + zp[2][gr][192 + ci] + zp[3][gr][192 + ci];
            const float ig = 1.f / (1.f + expf(-zi));
            const float fg = 1.f / (1.f + expf(-zf));
            const float gg = tanhf(zg);
            const float og = 1.f / (1.f + expf(-zo));
            const float cn = fg * cst + ig * gg;
            const float hn = og * tanhf(cn);
            if (tt < glen) { cst = cn; hreg = hn; pacc += hn; }
            hbD[(size_t)((s + 1) & 1) * B_ * H_ + gbrow * H_ + cg * 64 + gdd] = hreg;
        }
        __syncthreads();                 // drains vmem (stores in L2) before fence
        if (tid == 0) {
            __builtin_amdgcn_fence(__ATOMIC_RELEASE, "agent");
            atomicAdd(&tc[s], 1u);
        }
    }

    if (tid < 128)
        pool[gbrow * 512 + dir * 256 + cg * 64 + gdd] = pacc / (float)glen;
}

// ---------------------------------------------------------------------------
// Kernel 4: fc_hidden = relu(pool @ Wfc + bfc); out = fc_hidden @ Wout + bout
// ---------------------------------------------------------------------------
__global__ __launch_bounds__(256)
void k_fc(const float* __restrict__ pool, const float* __restrict__ Wfc,
          const float* __restrict__ bfc, const float* __restrict__ Wout,
          const float* __restrict__ bout, float* __restrict__ out)
{
    __shared__ float p_sh[512];
    __shared__ float red[8];

    const int tid = threadIdx.x;
    const int b   = blockIdx.x;

    p_sh[tid]       = pool[b * 512 + tid];
    p_sh[256 + tid] = pool[b * 512 + 256 + tid];
    __syncthreads();

    float acc = bfc[tid];
#pragma unroll 8
    for (int k = 0; k < 512; ++k)
        acc += p_sh[k] * Wfc[(size_t)k * H_ + tid];
    const float fh = fmaxf(acc, 0.f);

    float p0 = fh * Wout[tid * 2 + 0];
    float p1 = fh * Wout[tid * 2 + 1];
#pragma unroll
    for (int off = 32; off > 0; off >>= 1) {
        p0 += __shfl_down(p0, off);
        p1 += __shfl_down(p1, off);
    }
    const int wave = tid >> 6;
    if ((tid & 63) == 0) { red[wave * 2] = p0; red[wave * 2 + 1] = p1; }
    __syncthreads();
    if (tid == 0) {
        out[b * 2 + 0] = red[0] + red[2] + red[4] + red[6] + bout[0];
        out[b * 2 + 1] = red[1] + red[3] + red[5] + red[7] + bout[1];
    }
}

__global__ void k_sentinel(float* out, int n)
{
    const int i = blockIdx.x * blockDim.x + threadIdx.x;
    if (i < n) out[i] = 1.0e9f;
}

extern "C" void kernel_launch(void* const* d_in, const int* in_sizes, int n_in,
                              void* d_out, int out_size, void* d_ws, size_t ws_size,
                              hipStream_t stream)
{
    const float* emb  = (const float*)d_in[0];
    const float* Win  = (const float*)d_in[1];
    const float* bin  = (const float*)d_in[2];
    const float* Wihf = (const float*)d_in[3];
    const float* Whhf = (const float*)d_in[4];
    const float* blf  = (const float*)d_in[5];
    const float* Wihb = (const float*)d_in[6];
    const float* Whhb = (const float*)d_in[7];
    const float* blb  = (const float*)d_in[8];
    const float* Wfc  = (const float*)d_in[9];
    const float* bfc  = (const float*)d_in[10];
    const float* Wout = (const float*)d_in[11];
    const float* bout = (const float*)d_in[12];
    const int*   x    = (const int*)d_in[13];
    const int*   lens = (const int*)d_in[15];
    float*       out  = (float*)d_out;

    const size_t need = ((size_t)M_ * H_ + 2 * (size_t)M_ * G4_) * sizeof(float);
    if (ws_size < need) {
        hipLaunchKernelGGL(k_sentinel, dim3(1), dim3(64), 0, stream, out, out_size);
        return;
    }

    float* z  = (float*)d_ws;                    // [16384,256] (dead after k2)
    float* Pf = z + (size_t)M_ * H_;             // [16384,1024]
    float* Pb = Pf + (size_t)M_ * G4_;           // [16384,1024]

    // overlay (inside z region; init runs after k2 has consumed z)
    float*        hb   = (float*)d_ws;           // [2][2][32][256] = 128 KB
    unsigned int* ctr  = (unsigned int*)(hb + 2 * 2 * B_ * H_);  // [32][512]
    float*        pool = (float*)(ctr + NTEAM * 512);            // [32][512]

    hipLaunchKernelGGL(k_embed_proj, dim3(2, 128), dim3(256), 0, stream,
                       emb, Win, bin, x, z);
    hipLaunchKernelGGL(k_in_proj, dim3(8, 128, 2), dim3(256), 0, stream,
                       z, Wihf, blf, Wihb, blb, Pf, Pb);
    hipLaunchKernelGGL(k_init, dim3(128), dim3(256), 0, stream, hb, ctr);
    hipLaunchKernelGGL(k_lstm_persist, dim3(NWG), dim3(THR), 0, stream,
                       Pf, Pb, Whhf, Whhb, lens, hb, ctr, pool);
    hipLaunchKernelGGL(k_fc, dim3(32), dim3(256), 0, stream,
                       pool, Wfc, bfc, Wout, bout, out);
}

// Round 3
// 1519.976 us; speedup vs baseline: 2.9235x; 1.7795x over previous
//
#include <hip/hip_runtime.h>
#include <math.h>

#define B_    32
#define T_    512
#define WDIM_ 300
#define H_    256
#define G4_   1024            // 4*H
#define M_    (B_ * T_)       // 16384

// persistent-LSTM geometry
#define NBG   16              // batch groups (2 rows each)
#define NCG   4               // col groups per team (64 d's each)
#define NWG   128             // 2 dirs * NBG * NCG
#define THR   512
#define HXN   (2 * 2 * B_ * H_)   // packets: [buf][dir][32][256]

// repeat macros -> compile-time-constant indices (SROA-safe register arrays)
#define RPT4(M, b)  M(b) M((b)+1) M((b)+2) M((b)+3)
#define RPT16(M, b) RPT4(M, b) RPT4(M, (b)+4) RPT4(M, (b)+8) RPT4(M, (b)+12)
#define RPT64(M)    RPT16(M, 0) RPT16(M, 16) RPT16(M, 32) RPT16(M, 48)

// ---------------------------------------------------------------------------
// Kernel 1: z = relu(emb[x] @ W_in + b_in)   [16384,300]@[300,256]
// ---------------------------------------------------------------------------
__global__ __launch_bounds__(256)
void k_embed_proj(const float* __restrict__ emb, const float* __restrict__ Win,
                  const float* __restrict__ bin, const int* __restrict__ x,
                  float* __restrict__ z)
{
    __shared__ float Ash[16][132];
    __shared__ float Bsh[16][132];
    __shared__ int   rows[128];

    const int tid = threadIdx.x;
    const int tx = tid & 15, ty = tid >> 4;
    const int rm = blockIdx.y * 128;
    const int cn = blockIdx.x * 128;

    if (tid < 128) rows[tid] = x[rm + tid];
    __syncthreads();

    float acc[8][8];
#pragma unroll
    for (int i = 0; i < 8; ++i)
#pragma unroll
        for (int j = 0; j < 8; ++j) acc[i][j] = 0.f;

    for (int kc = 0; kc < 19; ++kc) {
        const int k0 = kc * 16;
#pragma unroll
        for (int e = 0; e < 8; ++e) {
            const int idx = e * 256 + tid;
            const int r = idx >> 4, kk = idx & 15;
            const int k = k0 + kk;
            const int v = rows[r];
            Ash[kk][r] = (k < WDIM_) ? emb[(size_t)v * WDIM_ + k] : 0.f;
        }
#pragma unroll
        for (int e = 0; e < 8; ++e) {
            const int idx = e * 256 + tid;
            const int kk = idx >> 7, n = idx & 127;
            const int k = k0 + kk;
            Bsh[kk][n] = (k < WDIM_) ? Win[(size_t)k * H_ + cn + n] : 0.f;
        }
        __syncthreads();
#pragma unroll
        for (int kk = 0; kk < 16; ++kk) {
            float a[8], bb[8];
#pragma unroll
            for (int i = 0; i < 8; ++i) a[i] = Ash[kk][ty * 8 + i];
#pragma unroll
            for (int j = 0; j < 8; ++j) bb[j] = Bsh[kk][tx * 8 + j];
#pragma unroll
            for (int i = 0; i < 8; ++i)
#pragma unroll
                for (int j = 0; j < 8; ++j) acc[i][j] += a[i] * bb[j];
        }
        __syncthreads();
    }

#pragma unroll
    for (int i = 0; i < 8; ++i) {
        const int row = rm + ty * 8 + i;
#pragma unroll
        for (int j = 0; j < 8; ++j) {
            const int col = cn + tx * 8 + j;
            z[(size_t)row * H_ + col] = fmaxf(acc[i][j] + bin[col], 0.f);
        }
    }
}

// ---------------------------------------------------------------------------
// Kernel 2: P_d = z @ Wih_d + bl_d  (both directions via blockIdx.z)
// ---------------------------------------------------------------------------
__global__ __launch_bounds__(256)
void k_in_proj(const float* __restrict__ z,
               const float* __restrict__ Wf, const float* __restrict__ blf,
               const float* __restrict__ Wb, const float* __restrict__ blb,
               float* __restrict__ Pf, float* __restrict__ Pb)
{
    const float* W  = blockIdx.z ? Wb  : Wf;
    const float* bl = blockIdx.z ? blb : blf;
    float*       P  = blockIdx.z ? Pb  : Pf;

    __shared__ float Ash[16][132];
    __shared__ float Bsh[16][132];

    const int tid = threadIdx.x;
    const int tx = tid & 15, ty = tid >> 4;
    const int rm = blockIdx.y * 128;
    const int cn = blockIdx.x * 128;

    float acc[8][8];
#pragma unroll
    for (int i = 0; i < 8; ++i)
#pragma unroll
        for (int j = 0; j < 8; ++j) acc[i][j] = 0.f;

    for (int kc = 0; kc < 16; ++kc) {
        const int k0 = kc * 16;
#pragma unroll
        for (int e = 0; e < 8; ++e) {
            const int idx = e * 256 + tid;
            const int r = idx >> 4, kk = idx & 15;
            Ash[kk][r] = z[(size_t)(rm + r) * H_ + k0 + kk];
        }
#pragma unroll
        for (int e = 0; e < 8; ++e) {
            const int idx = e * 256 + tid;
            const int kk = idx >> 7, n = idx & 127;
            Bsh[kk][n] = W[(size_t)(k0 + kk) * G4_ + cn + n];
        }
        __syncthreads();
#pragma unroll
        for (int kk = 0; kk < 16; ++kk) {
            float a[8], bb[8];
#pragma unroll
            for (int i = 0; i < 8; ++i) a[i] = Ash[kk][ty * 8 + i];
#pragma unroll
            for (int j = 0; j < 8; ++j) bb[j] = Bsh[kk][tx * 8 + j];
#pragma unroll
            for (int i = 0; i < 8; ++i)
#pragma unroll
                for (int j = 0; j < 8; ++j) acc[i][j] += a[i] * bb[j];
        }
        __syncthreads();
    }

#pragma unroll
    for (int i = 0; i < 8; ++i) {
        const int row = rm + ty * 8 + i;
#pragma unroll
        for (int j = 0; j < 8; ++j) {
            const int col = cn + tx * 8 + j;
            P[(size_t)row * G4_ + col] = acc[i][j] + bl[col];
        }
    }
}

// ---------------------------------------------------------------------------
// Init: zero h packet buffers ({h=0, tag=0} == initial state)
// ---------------------------------------------------------------------------
__global__ void k_init(unsigned long long* __restrict__ hx)
{
    const int i = blockIdx.x * blockDim.x + threadIdx.x;
    if (i < HXN) hx[i] = 0ull;
}

// ---------------------------------------------------------------------------
// Kernel 3: persistent bidirectional LSTM recurrence, fence-free.
// WG = (dir, batch-pair bg, colgroup cg). Team = 4 colgroups (no fences:
// h published as {h,tag} 8-byte relaxed agent-scope atomic packets,
// double-buffered by step parity; readers poll tag>=s — the h rides in the
// same atomic 64-bit load, so no release/acquire is needed).
// Whh slice register-resident: 64 float2 = 128 VGPRs/thread, all indices
// compile-time constants via RPT macros (SROA-proof).
// ---------------------------------------------------------------------------
__global__ __launch_bounds__(THR, 2)
void k_lstm_persist(const float* __restrict__ Pf, const float* __restrict__ Pb,
                    const float* __restrict__ Whf, const float* __restrict__ Whb,
                    const int* __restrict__ lengths,
                    unsigned long long* __restrict__ hx,
                    float* __restrict__ pool)
{
    __shared__ float h_sh[2][256];
    __shared__ float zp[4][2][256];   // [ksplit][row][local gate-col]

    const int tid = threadIdx.x;
    const int wg  = blockIdx.x;
    const int bg  = wg & 15;
    const int dir = (wg >> 4) & 1;
    const int cg  = wg >> 5;          // 0..3

    const float* P   = dir ? Pb  : Pf;
    const float* Whh = dir ? Whb : Whf;

    const int brow0 = bg * 2;
    const int len0 = lengths[brow0], len1 = lengths[brow0 + 1];
    const int tmax = max(len0, len1);

    // GEMV mapping: q = k-quarter, c0 = local col pair base in [0,256)
    const int q   = tid >> 7;
    const int c0  = (tid & 127) * 2;
    const int g0  = c0 >> 6;
    const int dd0 = c0 & 63;
    const int gcol0 = g0 * 256 + cg * 64 + dd0;   // even; pair never crosses gate
    const int q64 = q * 64;

    // persistent W slice: 64 float2 = 128 VGPRs (constant indices only!)
    float2 wv[64];
    {
        const float* wp = Whh + (size_t)q64 * G4_ + gcol0;
#define LOADW(k) wv[k] = *(const float2*)(wp + (size_t)(k) * G4_);
        RPT64(LOADW)
#undef LOADW
    }

    // gate mapping (tid < 128): row gr, hidden index gdd
    const int gr    = tid >> 6;
    const int gdd   = tid & 63;
    const int gbrow = brow0 + gr;
    const int glen  = gr ? len1 : len0;
    float cst = 0.f, hreg = 0.f, pacc = 0.f;

    // h-packet loader mapping (all 512 threads): row lrow, index ld
    const int lrow = tid >> 8;
    const int ld   = tid & 255;
    unsigned long long* slotR = hx + ((size_t)dir * 32 + brow0 + lrow) * 256 + ld;
    unsigned long long* slotW = hx + ((size_t)dir * 32 + gbrow) * 256 + cg * 64 + gdd;
    const size_t bufStride = (size_t)2 * B_ * H_;   // packets per parity

    for (int s = 0; s < tmax; ++s) {
        const int tt = dir ? (tmax - 1 - s) : s;

        // prefetch input projection for this step (independent of the poll)
        float pv0 = 0.f, pv1 = 0.f, pv2 = 0.f, pv3 = 0.f;
        if (tid < 128) {
            const float* pr = P + (size_t)(gbrow * T_ + tt) * G4_ + cg * 64 + gdd;
            pv0 = pr[0]; pv1 = pr[256]; pv2 = pr[512]; pv3 = pr[768];
        }

        // poll h_{s-1} packets (tag s) and stage into LDS
        {
            const unsigned long long* sp = slotR + (size_t)(s & 1) * bufStride;
            unsigned long long pk = __hip_atomic_load(sp, __ATOMIC_RELAXED,
                                                      __HIP_MEMORY_SCOPE_AGENT);
            while ((unsigned)(pk >> 32) < (unsigned)s) {
                __builtin_amdgcn_s_sleep(1);
                pk = __hip_atomic_load(sp, __ATOMIC_RELAXED,
                                       __HIP_MEMORY_SCOPE_AGENT);
            }
            h_sh[lrow][ld] = __uint_as_float((unsigned)pk);
        }
        __syncthreads();

        // GEMV: 2 rows x 2 cols over k in [64q, 64q+64)
        {
            const float* h0 = &h_sh[0][q64];
            const float* h1 = &h_sh[1][q64];
            float a00 = 0.f, a01 = 0.f, a10 = 0.f, a11 = 0.f;
#define GEMV4(k4) { \
            const float4 hv0 = *(const float4*)(h0 + 4 * (k4)); \
            const float4 hv1 = *(const float4*)(h1 + 4 * (k4)); \
            a00 += hv0.x * wv[4*(k4)  ].x; a01 += hv0.x * wv[4*(k4)  ].y; \
            a10 += hv1.x * wv[4*(k4)  ].x; a11 += hv1.x * wv[4*(k4)  ].y; \
            a00 += hv0.y * wv[4*(k4)+1].x; a01 += hv0.y * wv[4*(k4)+1].y; \
            a10 += hv1.y * wv[4*(k4)+1].x; a11 += hv1.y * wv[4*(k4)+1].y; \
            a00 += hv0.z * wv[4*(k4)+2].x; a01 += hv0.z * wv[4*(k4)+2].y; \
            a10 += hv1.z * wv[4*(k4)+2].x; a11 += hv1.z * wv[4*(k4)+2].y; \
            a00 += hv0.w * wv[4*(k4)+3].x; a01 += hv0.w * wv[4*(k4)+3].y; \
            a10 += hv1.w * wv[4*(k4)+3].x; a11 += hv1.w * wv[4*(k4)+3].y; }
            RPT16(GEMV4, 0)
#undef GEMV4
            *(float2*)&zp[q][0][c0] = make_float2(a00, a01);
            *(float2*)&zp[q][1][c0] = make_float2(a10, a11);
        }
        __syncthreads();

        // gates + state update + h-packet publish (tag s+1, parity (s+1)&1)
        if (tid < 128) {
            const int ci = gdd;
            float zi = pv0 + zp[0][gr][ci]       + zp[1][gr][ci]       + zp[2][gr][ci]       + zp[3][gr][ci];
            float zf = pv1 + zp[0][gr][64 + ci]  + zp[1][gr][64 + ci]  + zp[2][gr][64 + ci]  + zp[3][gr][64 + ci];
            float zg = pv2 + zp[0][gr][128 + ci] + zp[1][gr][128 + ci] + zp[2][gr][128 + ci] + zp[3][gr][128 + ci];
            float zo = pv3 + zp[0][gr][192 + ci] + zp[1][gr][192 + ci] + zp[2][gr][192 + ci] + zp[3][gr][192 + ci];
            const float ig = 1.f / (1.f + expf(-zi));
            const float fg = 1.f / (1.f + expf(-zf));
            const float gg = tanhf(zg);
            const float og = 1.f / (1.f + expf(-zo));
            const float cn = fg * cst + ig * gg;
            const float hn = og * tanhf(cn);
            if (tt < glen) { cst = cn; hreg = hn; pacc += hn; }
            const unsigned long long opk =
                ((unsigned long long)(unsigned)(s + 1) << 32) |
                (unsigned long long)__float_as_uint(hreg);
            __hip_atomic_store(slotW + (size_t)((s + 1) & 1) * bufStride, opk,
                               __ATOMIC_RELAXED, __HIP_MEMORY_SCOPE_AGENT);
        }
        // no trailing barrier needed: zp is only rewritten after the next
        // step's post-poll __syncthreads, which gate threads reach only
        // after finishing this block (program order).
    }

    if (tid < 128)
        pool[gbrow * 512 + dir * 256 + cg * 64 + gdd] = pacc / (float)glen;
}

// ---------------------------------------------------------------------------
// Kernel 4: fc_hidden = relu(pool @ Wfc + bfc); out = fc_hidden @ Wout + bout
// ---------------------------------------------------------------------------
__global__ __launch_bounds__(256)
void k_fc(const float* __restrict__ pool, const float* __restrict__ Wfc,
          const float* __restrict__ bfc, const float* __restrict__ Wout,
          const float* __restrict__ bout, float* __restrict__ out)
{
    __shared__ float p_sh[512];
    __shared__ float red[8];

    const int tid = threadIdx.x;
    const int b   = blockIdx.x;

    p_sh[tid]       = pool[b * 512 + tid];
    p_sh[256 + tid] = pool[b * 512 + 256 + tid];
    __syncthreads();

    float acc = bfc[tid];
#pragma unroll 8
    for (int k = 0; k < 512; ++k)
        acc += p_sh[k] * Wfc[(size_t)k * H_ + tid];
    const float fh = fmaxf(acc, 0.f);

    float p0 = fh * Wout[tid * 2 + 0];
    float p1 = fh * Wout[tid * 2 + 1];
#pragma unroll
    for (int off = 32; off > 0; off >>= 1) {
        p0 += __shfl_down(p0, off);
        p1 += __shfl_down(p1, off);
    }
    const int wave = tid >> 6;
    if ((tid & 63) == 0) { red[wave * 2] = p0; red[wave * 2 + 1] = p1; }
    __syncthreads();
    if (tid == 0) {
        out[b * 2 + 0] = red[0] + red[2] + red[4] + red[6] + bout[0];
        out[b * 2 + 1] = red[1] + red[3] + red[5] + red[7] + bout[1];
    }
}

__global__ void k_sentinel(float* out, int n)
{
    const int i = blockIdx.x * blockDim.x + threadIdx.x;
    if (i < n) out[i] = 1.0e9f;
}

extern "C" void kernel_launch(void* const* d_in, const int* in_sizes, int n_in,
                              void* d_out, int out_size, void* d_ws, size_t ws_size,
                              hipStream_t stream)
{
    const float* emb  = (const float*)d_in[0];
    const float* Win  = (const float*)d_in[1];
    const float* bin  = (const float*)d_in[2];
    const float* Wihf = (const float*)d_in[3];
    const float* Whhf = (const float*)d_in[4];
    const float* blf  = (const float*)d_in[5];
    const float* Wihb = (const float*)d_in[6];
    const float* Whhb = (const float*)d_in[7];
    const float* blb  = (const float*)d_in[8];
    const float* Wfc  = (const float*)d_in[9];
    const float* bfc  = (const float*)d_in[10];
    const float* Wout = (const float*)d_in[11];
    const float* bout = (const float*)d_in[12];
    const int*   x    = (const int*)d_in[13];
    const int*   lens = (const int*)d_in[15];
    float*       out  = (float*)d_out;

    const size_t need = ((size_t)M_ * H_ + 2 * (size_t)M_ * G4_) * sizeof(float);
    if (ws_size < need) {
        hipLaunchKernelGGL(k_sentinel, dim3(1), dim3(64), 0, stream, out, out_size);
        return;
    }

    float* z  = (float*)d_ws;                    // [16384,256] (dead after k2)
    float* Pf = z + (size_t)M_ * H_;             // [16384,1024]
    float* Pb = Pf + (size_t)M_ * G4_;           // [16384,1024]

    // overlay inside z region (init runs after k2 has consumed z)
    unsigned long long* hx   = (unsigned long long*)d_ws;        // [2][2][32][256] packets
    float*              pool = (float*)(hx + HXN);               // [32][512]

    hipLaunchKernelGGL(k_embed_proj, dim3(2, 128), dim3(256), 0, stream,
                       emb, Win, bin, x, z);
    hipLaunchKernelGGL(k_in_proj, dim3(8, 128, 2), dim3(256), 0, stream,
                       z, Wihf, blf, Wihb, blb, Pf, Pb);
    hipLaunchKernelGGL(k_init, dim3(128), dim3(256), 0, stream, hx);
    hipLaunchKernelGGL(k_lstm_persist, dim3(NWG), dim3(THR), 0, stream,
                       Pf, Pb, Whhf, Whhb, lens, hx, pool);
    hipLaunchKernelGGL(k_fc, dim3(32), dim3(256), 0, stream,
                       pool, Wfc, bfc, Wout, bout, out);
}

// Round 4
// 1379.629 us; speedup vs baseline: 3.2209x; 1.1017x over previous
//
#include <hip/hip_runtime.h>
#include <math.h>

#define B_    32
#define T_    512
#define WDIM_ 300
#define H_    256
#define G4_   1024            // 4*H
#define M_    (B_ * T_)       // 16384

// persistent-LSTM geometry: team = 8 WGs covering one (dir, batch-pair)
#define NCG   8               // col groups per team (32 d's each)
#define NWG   256             // 2 dirs * 16 batch-pairs * NCG
#define THR   512
#define HXN   (2 * 2 * B_ * H_)   // packets: [buf][dir][32][256]

// repeat macros -> compile-time-constant indices (SROA-safe register arrays)
#define RPT4(M, b)  M(b) M((b)+1) M((b)+2) M((b)+3)
#define RPT16(M, b) RPT4(M, b) RPT4(M, (b)+4) RPT4(M, (b)+8) RPT4(M, (b)+12)
#define RPT64(M)    RPT16(M, 0) RPT16(M, 16) RPT16(M, 32) RPT16(M, 48)

// ---------------------------------------------------------------------------
// Kernel 1: z = relu(emb[x] @ W_in + b_in)   [16384,300]@[300,256]
// ---------------------------------------------------------------------------
__global__ __launch_bounds__(256)
void k_embed_proj(const float* __restrict__ emb, const float* __restrict__ Win,
                  const float* __restrict__ bin, const int* __restrict__ x,
                  float* __restrict__ z)
{
    __shared__ float Ash[16][132];
    __shared__ float Bsh[16][132];
    __shared__ int   rows[128];

    const int tid = threadIdx.x;
    const int tx = tid & 15, ty = tid >> 4;
    const int rm = blockIdx.y * 128;
    const int cn = blockIdx.x * 128;

    if (tid < 128) rows[tid] = x[rm + tid];
    __syncthreads();

    float acc[8][8];
#pragma unroll
    for (int i = 0; i < 8; ++i)
#pragma unroll
        for (int j = 0; j < 8; ++j) acc[i][j] = 0.f;

    for (int kc = 0; kc < 19; ++kc) {
        const int k0 = kc * 16;
#pragma unroll
        for (int e = 0; e < 8; ++e) {
            const int idx = e * 256 + tid;
            const int r = idx >> 4, kk = idx & 15;
            const int k = k0 + kk;
            const int v = rows[r];
            Ash[kk][r] = (k < WDIM_) ? emb[(size_t)v * WDIM_ + k] : 0.f;
        }
#pragma unroll
        for (int e = 0; e < 8; ++e) {
            const int idx = e * 256 + tid;
            const int kk = idx >> 7, n = idx & 127;
            const int k = k0 + kk;
            Bsh[kk][n] = (k < WDIM_) ? Win[(size_t)k * H_ + cn + n] : 0.f;
        }
        __syncthreads();
#pragma unroll
        for (int kk = 0; kk < 16; ++kk) {
            float a[8], bb[8];
#pragma unroll
            for (int i = 0; i < 8; ++i) a[i] = Ash[kk][ty * 8 + i];
#pragma unroll
            for (int j = 0; j < 8; ++j) bb[j] = Bsh[kk][tx * 8 + j];
#pragma unroll
            for (int i = 0; i < 8; ++i)
#pragma unroll
                for (int j = 0; j < 8; ++j) acc[i][j] += a[i] * bb[j];
        }
        __syncthreads();
    }

#pragma unroll
    for (int i = 0; i < 8; ++i) {
        const int row = rm + ty * 8 + i;
#pragma unroll
        for (int j = 0; j < 8; ++j) {
            const int col = cn + tx * 8 + j;
            z[(size_t)row * H_ + col] = fmaxf(acc[i][j] + bin[col], 0.f);
        }
    }
}

// ---------------------------------------------------------------------------
// Kernel 2: P_d = z @ Wih_d + bl_d  (both directions via blockIdx.z)
// ---------------------------------------------------------------------------
__global__ __launch_bounds__(256)
void k_in_proj(const float* __restrict__ z,
               const float* __restrict__ Wf, const float* __restrict__ blf,
               const float* __restrict__ Wb, const float* __restrict__ blb,
               float* __restrict__ Pf, float* __restrict__ Pb)
{
    const float* W  = blockIdx.z ? Wb  : Wf;
    const float* bl = blockIdx.z ? blb : blf;
    float*       P  = blockIdx.z ? Pb  : Pf;

    __shared__ float Ash[16][132];
    __shared__ float Bsh[16][132];

    const int tid = threadIdx.x;
    const int tx = tid & 15, ty = tid >> 4;
    const int rm = blockIdx.y * 128;
    const int cn = blockIdx.x * 128;

    float acc[8][8];
#pragma unroll
    for (int i = 0; i < 8; ++i)
#pragma unroll
        for (int j = 0; j < 8; ++j) acc[i][j] = 0.f;

    for (int kc = 0; kc < 16; ++kc) {
        const int k0 = kc * 16;
#pragma unroll
        for (int e = 0; e < 8; ++e) {
            const int idx = e * 256 + tid;
            const int r = idx >> 4, kk = idx & 15;
            Ash[kk][r] = z[(size_t)(rm + r) * H_ + k0 + kk];
        }
#pragma unroll
        for (int e = 0; e < 8; ++e) {
            const int idx = e * 256 + tid;
            const int kk = idx >> 7, n = idx & 127;
            Bsh[kk][n] = W[(size_t)(k0 + kk) * G4_ + cn + n];
        }
        __syncthreads();
#pragma unroll
        for (int kk = 0; kk < 16; ++kk) {
            float a[8], bb[8];
#pragma unroll
            for (int i = 0; i < 8; ++i) a[i] = Ash[kk][ty * 8 + i];
#pragma unroll
            for (int j = 0; j < 8; ++j) bb[j] = Bsh[kk][tx * 8 + j];
#pragma unroll
            for (int i = 0; i < 8; ++i)
#pragma unroll
                for (int j = 0; j < 8; ++j) acc[i][j] += a[i] * bb[j];
        }
        __syncthreads();
    }

#pragma unroll
    for (int i = 0; i < 8; ++i) {
        const int row = rm + ty * 8 + i;
#pragma unroll
        for (int j = 0; j < 8; ++j) {
            const int col = cn + tx * 8 + j;
            P[(size_t)row * G4_ + col] = acc[i][j] + bl[col];
        }
    }
}

// ---------------------------------------------------------------------------
// Init: zero h packet buffers ({h=0, tag=0} == initial state)
// ---------------------------------------------------------------------------
__global__ void k_init(unsigned long long* __restrict__ hx)
{
    const int i = blockIdx.x * blockDim.x + threadIdx.x;
    if (i < HXN) hx[i] = 0ull;
}

// ---------------------------------------------------------------------------
// Kernel 3: persistent bidirectional LSTM recurrence, fence-free.
// WG = (dir, batch-pair bg, colgroup cg of 32 d's). Team = 8 colgroups.
// h published as {h,tag} 8-byte relaxed agent-scope atomic packets, double-
// buffered by step parity; readers poll tag>=s (h rides in the same 64-bit
// load -> no release/acquire fences). Teammates are blockIdx stride-32 ->
// same XCD slot under round-robin dispatch -> exchange stays in one L2.
// Whh slice register-resident: 64 floats/thread, constant indices (SROA).
// All 256 WGs co-resident (~100 VGPR, 512 thr -> >=2 WG/CU capacity).
// ---------------------------------------------------------------------------
__global__ __launch_bounds__(THR, 2)
void k_lstm_persist(const float* __restrict__ Pf, const float* __restrict__ Pb,
                    const float* __restrict__ Whf, const float* __restrict__ Whb,
                    const int* __restrict__ lengths,
                    unsigned long long* __restrict__ hx,
                    float* __restrict__ pool)
{
    __shared__ float h_sh[2][256];
    __shared__ float zp[4][2][128];   // [ksplit][row][local gate-col]

    const int tid = threadIdx.x;
    const int wg  = blockIdx.x;
    const int bg  = wg & 15;
    const int dir = (wg >> 4) & 1;
    const int cg  = wg >> 5;          // 0..7

    const float* P   = dir ? Pb  : Pf;
    const float* Whh = dir ? Whb : Whf;

    const int brow0 = bg * 2;
    const int len0 = lengths[brow0], len1 = lengths[brow0 + 1];
    const int tmax = max(len0, len1);

    // GEMV mapping: q = k-quarter, cl = local col in [0,128)
    const int q   = tid >> 7;
    const int cl  = tid & 127;
    const int g0  = cl >> 5;
    const int dd0 = cl & 31;
    const int gcol = g0 * 256 + cg * 32 + dd0;    // global column
    const int q64 = q * 64;

    // persistent W slice: 64 floats (constant indices only!)
    float wv[64];
    {
        const float* wp = Whh + (size_t)q64 * G4_ + gcol;
#define LOADW(k) wv[k] = wp[(size_t)(k) * G4_];
        RPT64(LOADW)
#undef LOADW
    }

    // gate mapping (tid < 64): row gr, local hidden index gd
    const int gr    = tid >> 5;
    const int gd    = tid & 31;
    const int gbrow = brow0 + gr;
    const int glen  = gr ? len1 : len0;
    float cst = 0.f, hreg = 0.f, pacc = 0.f;

    // h-packet loader mapping (all 512 threads): row lrow, index ld
    const int lrow = tid >> 8;
    const int ld   = tid & 255;
    unsigned long long* slotR = hx + ((size_t)dir * 32 + brow0 + lrow) * 256 + ld;
    unsigned long long* slotW = hx + ((size_t)dir * 32 + gbrow) * 256 + cg * 32 + gd;
    const size_t bufStride = (size_t)2 * B_ * H_;   // packets per parity

    for (int s = 0; s < tmax; ++s) {
        const int tt = dir ? (tmax - 1 - s) : s;

        // prefetch input projection for this step (independent of the poll)
        float pv0 = 0.f, pv1 = 0.f, pv2 = 0.f, pv3 = 0.f;
        if (tid < 64) {
            const float* pr = P + (size_t)(gbrow * T_ + tt) * G4_ + cg * 32 + gd;
            pv0 = pr[0]; pv1 = pr[256]; pv2 = pr[512]; pv3 = pr[768];
        }

        // poll h_{s-1} packets (tag s) and stage into LDS
        {
            const unsigned long long* sp = slotR + (size_t)(s & 1) * bufStride;
            unsigned long long pk = __hip_atomic_load(sp, __ATOMIC_RELAXED,
                                                      __HIP_MEMORY_SCOPE_AGENT);
            while ((unsigned)(pk >> 32) < (unsigned)s) {
                __builtin_amdgcn_s_sleep(1);
                pk = __hip_atomic_load(sp, __ATOMIC_RELAXED,
                                       __HIP_MEMORY_SCOPE_AGENT);
            }
            h_sh[lrow][ld] = __uint_as_float((unsigned)pk);
        }
        __syncthreads();

        // GEMV: 2 rows x 1 col over k in [64q, 64q+64)
        {
            const float* h0 = &h_sh[0][q64];
            const float* h1 = &h_sh[1][q64];
            float a0 = 0.f, a1 = 0.f;
#define GEMV4(k4) { \
            const float4 hv0 = *(const float4*)(h0 + 4 * (k4)); \
            const float4 hv1 = *(const float4*)(h1 + 4 * (k4)); \
            a0 += hv0.x * wv[4*(k4)  ]; a1 += hv1.x * wv[4*(k4)  ]; \
            a0 += hv0.y * wv[4*(k4)+1]; a1 += hv1.y * wv[4*(k4)+1]; \
            a0 += hv0.z * wv[4*(k4)+2]; a1 += hv1.z * wv[4*(k4)+2]; \
            a0 += hv0.w * wv[4*(k4)+3]; a1 += hv1.w * wv[4*(k4)+3]; }
            RPT16(GEMV4, 0)
#undef GEMV4
            zp[q][0][cl] = a0;
            zp[q][1][cl] = a1;
        }
        __syncthreads();

        // gates + state update + h-packet publish (tag s+1, parity (s+1)&1)
        if (tid < 64) {
            float zi = pv0 + zp[0][gr][gd]      + zp[1][gr][gd]      + zp[2][gr][gd]      + zp[3][gr][gd];
            float zf = pv1 + zp[0][gr][32 + gd] + zp[1][gr][32 + gd] + zp[2][gr][32 + gd] + zp[3][gr][32 + gd];
            float zg = pv2 + zp[0][gr][64 + gd] + zp[1][gr][64 + gd] + zp[2][gr][64 + gd] + zp[3][gr][64 + gd];
            float zo = pv3 + zp[0][gr][96 + gd] + zp[1][gr][96 + gd] + zp[2][gr][96 + gd] + zp[3][gr][96 + gd];
            const float ig = 1.f / (1.f + expf(-zi));
            const float fg = 1.f / (1.f + expf(-zf));
            const float gg = tanhf(zg);
            const float og = 1.f / (1.f + expf(-zo));
            const float cn = fg * cst + ig * gg;
            const float hn = og * tanhf(cn);
            if (tt < glen) { cst = cn; hreg = hn; pacc += hn; }
            const unsigned long long opk =
                ((unsigned long long)(unsigned)(s + 1) << 32) |
                (unsigned long long)__float_as_uint(hreg);
            __hip_atomic_store(slotW + (size_t)((s + 1) & 1) * bufStride, opk,
                               __ATOMIC_RELAXED, __HIP_MEMORY_SCOPE_AGENT);
        }
        // no trailing barrier: zp of step s+1 is written only after the next
        // post-poll __syncthreads, which gate threads reach after this block.
    }

    if (tid < 64)
        pool[gbrow * 512 + dir * 256 + cg * 32 + gd] = pacc / (float)glen;
}

// ---------------------------------------------------------------------------
// Kernel 4: fc_hidden = relu(pool @ Wfc + bfc); out = fc_hidden @ Wout + bout
// ---------------------------------------------------------------------------
__global__ __launch_bounds__(256)
void k_fc(const float* __restrict__ pool, const float* __restrict__ Wfc,
          const float* __restrict__ bfc, const float* __restrict__ Wout,
          const float* __restrict__ bout, float* __restrict__ out)
{
    __shared__ float p_sh[512];
    __shared__ float red[8];

    const int tid = threadIdx.x;
    const int b   = blockIdx.x;

    p_sh[tid]       = pool[b * 512 + tid];
    p_sh[256 + tid] = pool[b * 512 + 256 + tid];
    __syncthreads();

    float acc = bfc[tid];
#pragma unroll 8
    for (int k = 0; k < 512; ++k)
        acc += p_sh[k] * Wfc[(size_t)k * H_ + tid];
    const float fh = fmaxf(acc, 0.f);

    float p0 = fh * Wout[tid * 2 + 0];
    float p1 = fh * Wout[tid * 2 + 1];
#pragma unroll
    for (int off = 32; off > 0; off >>= 1) {
        p0 += __shfl_down(p0, off);
        p1 += __shfl_down(p1, off);
    }
    const int wave = tid >> 6;
    if ((tid & 63) == 0) { red[wave * 2] = p0; red[wave * 2 + 1] = p1; }
    __syncthreads();
    if (tid == 0) {
        out[b * 2 + 0] = red[0] + red[2] + red[4] + red[6] + bout[0];
        out[b * 2 + 1] = red[1] + red[3] + red[5] + red[7] + bout[1];
    }
}

__global__ void k_sentinel(float* out, int n)
{
    const int i = blockIdx.x * blockDim.x + threadIdx.x;
    if (i < n) out[i] = 1.0e9f;
}

extern "C" void kernel_launch(void* const* d_in, const int* in_sizes, int n_in,
                              void* d_out, int out_size, void* d_ws, size_t ws_size,
                              hipStream_t stream)
{
    const float* emb  = (const float*)d_in[0];
    const float* Win  = (const float*)d_in[1];
    const float* bin  = (const float*)d_in[2];
    const float* Wihf = (const float*)d_in[3];
    const float* Whhf = (const float*)d_in[4];
    const float* blf  = (const float*)d_in[5];
    const float* Wihb = (const float*)d_in[6];
    const float* Whhb = (const float*)d_in[7];
    const float* blb  = (const float*)d_in[8];
    const float* Wfc  = (const float*)d_in[9];
    const float* bfc  = (const float*)d_in[10];
    const float* Wout = (const float*)d_in[11];
    const float* bout = (const float*)d_in[12];
    const int*   x    = (const int*)d_in[13];
    const int*   lens = (const int*)d_in[15];
    float*       out  = (float*)d_out;

    const size_t need = ((size_t)M_ * H_ + 2 * (size_t)M_ * G4_) * sizeof(float);
    if (ws_size < need) {
        hipLaunchKernelGGL(k_sentinel, dim3(1), dim3(64), 0, stream, out, out_size);
        return;
    }

    float* z  = (float*)d_ws;                    // [16384,256] (dead after k2)
    float* Pf = z + (size_t)M_ * H_;             // [16384,1024]
    float* Pb = Pf + (size_t)M_ * G4_;           // [16384,1024]

    // overlay inside z region (init runs after k2 has consumed z)
    unsigned long long* hx   = (unsigned long long*)d_ws;        // packets
    float*              pool = (float*)(hx + HXN);               // [32][512]

    hipLaunchKernelGGL(k_embed_proj, dim3(2, 128), dim3(256), 0, stream,
                       emb, Win, bin, x, z);
    hipLaunchKernelGGL(k_in_proj, dim3(8, 128, 2), dim3(256), 0, stream,
                       z, Wihf, blf, Wihb, blb, Pf, Pb);
    hipLaunchKernelGGL(k_init, dim3(128), dim3(256), 0, stream, hx);
    hipLaunchKernelGGL(k_lstm_persist, dim3(NWG), dim3(THR), 0, stream,
                       Pf, Pb, Whhf, Whhb, lens, hx, pool);
    hipLaunchKernelGGL(k_fc, dim3(32), dim3(256), 0, stream,
                       pool, Wfc, bfc, Wout, bout, out);
}